// Round 2
// baseline (562.469 us; speedup 1.0000x reference)
//
#include <hip/hip_runtime.h>

#define BB 4
#define CC 32
#define HH 128
#define WW 256
#define CR 85
#define EPSF 1e-5f

// Output offsets (elements): out0 @0, out1 @4194304, out2 @8388608, out3 @41943040
#define O1_OFF 4194304
#define O2_OFF 8388608
#define COST1 33554432   // elements per direction of cost / out2-3

typedef __attribute__((ext_vector_type(8))) short bf16x8;
typedef __attribute__((ext_vector_type(4))) float f32x4;
typedef __attribute__((ext_vector_type(4))) float f4v;

// ws layout (ushort bf16): Q[side][512][256][32] then K[side][512][256][32]
// side 0 = from x_left (Q_l, K_l), side 1 = from x_right (Q_r, K_r)
#define ARR (512 * 256 * 32)
#define WS_Q(side) ((side) * ARR)
#define WS_K(side) (2 * ARR + (side) * ARR)
#define WS_NEEDED (4ull * ARR * 2ull)   // bytes

static __device__ __forceinline__ unsigned short f2bf(float f) {
    unsigned u = __float_as_uint(f);
    unsigned r = (u + 0x7FFFu + ((u >> 16) & 1u)) >> 16;   // RNE
    return (unsigned short)r;
}

// ---------------- Kernel A: projections + 2*x outputs + bf16 Q/K to ws ----------------
__global__ __launch_bounds__(256, 4)
void proj_kernel(const float* __restrict__ x_left, const float* __restrict__ x_right,
                 const float* __restrict__ q_w, const float* __restrict__ q_b,
                 const float* __restrict__ q_gamma, const float* __restrict__ q_beta,
                 const float* __restrict__ q_mean, const float* __restrict__ q_var,
                 const float* __restrict__ k_w, const float* __restrict__ k_b,
                 const float* __restrict__ k_gamma, const float* __restrict__ k_beta,
                 const float* __restrict__ k_mean, const float* __restrict__ k_var,
                 float* __restrict__ out, unsigned short* __restrict__ ws)
{
    __shared__ float wq[CC][CC];   // [c][o] BN-folded
    __shared__ float wk[CC][CC];
    __shared__ float bq[CC], bk[CC], sq[CC], sk[CC];

    const int t    = threadIdx.x;       // pixel within row
    const int side = blockIdx.x >> 9;   // 0 = left, 1 = right
    const int bh   = blockIdx.x & 511;

    if (t < CC) {
        float qs = q_gamma[t] * rsqrtf(q_var[t] + EPSF);
        float ks = k_gamma[t] * rsqrtf(k_var[t] + EPSF);
        sq[t] = qs; sk[t] = ks;
        bq[t] = q_b[t] * qs + q_beta[t] - q_mean[t] * qs;
        bk[t] = k_b[t] * ks + k_beta[t] - k_mean[t] * ks;
    }
    __syncthreads();
    for (int r = t; r < CC * CC; r += 256) {
        int o = r >> 5, c = r & 31;
        wq[c][o] = q_w[r] * sq[o];
        wk[c][o] = k_w[r] * sk[o];
    }
    __syncthreads();

    float q[CC], k[CC];
    #pragma unroll
    for (int o = 0; o < CC; ++o) { q[o] = bq[o]; k[o] = bk[o]; }

    const float* x = side ? x_right : x_left;
    const int b = bh >> 7, h = bh & 127;
    const int xbase = (b * CC * HH + h) * WW + t;
    float* outx = out + side * O1_OFF;

    #pragma unroll 4
    for (int c = 0; c < CC; ++c) {
        int idx = xbase + c * (HH * WW);
        float xv = __builtin_nontemporal_load(x + idx);
        __builtin_nontemporal_store(2.0f * xv, outx + idx);
        #pragma unroll
        for (int o = 0; o < CC; ++o) {
            q[o] += xv * wq[c][o];
            k[o] += xv * wk[c][o];
        }
    }

    unsigned short* qdst = ws + WS_Q(side) + (bh * WW + t) * CC;
    unsigned short* kdst = ws + WS_K(side) + (bh * WW + t) * CC;
    #pragma unroll
    for (int g = 0; g < 4; ++g) {
        uint4 vq, vk;
        vq.x = f2bf(q[8*g+0]) | ((unsigned)f2bf(q[8*g+1]) << 16);
        vq.y = f2bf(q[8*g+2]) | ((unsigned)f2bf(q[8*g+3]) << 16);
        vq.z = f2bf(q[8*g+4]) | ((unsigned)f2bf(q[8*g+5]) << 16);
        vq.w = f2bf(q[8*g+6]) | ((unsigned)f2bf(q[8*g+7]) << 16);
        vk.x = f2bf(k[8*g+0]) | ((unsigned)f2bf(k[8*g+1]) << 16);
        vk.y = f2bf(k[8*g+2]) | ((unsigned)f2bf(k[8*g+3]) << 16);
        vk.z = f2bf(k[8*g+4]) | ((unsigned)f2bf(k[8*g+5]) << 16);
        vk.w = f2bf(k[8*g+6]) | ((unsigned)f2bf(k[8*g+7]) << 16);
        ((uint4*)qdst)[g] = vq;
        ((uint4*)kdst)[g] = vk;
    }
}

// ---------------- Kernel B: MFMA scores + cost stream (register-resident) ----------------
// block = one (dir, bh, 32-row tile). Swapped-operand MFMA: acc = mfma(K_frag, Q_frag)
// puts 4 CONSECUTIVE COLUMNS of S in each lane's acc -> band-add directly against a
// float4 of cost in registers. No Sb exchange, 1 barrier total, LDS = 10.25 KB.
// Panel ownership: wave w owns absolute 32-col panel pw = (wbase>>5)+w (its MFMA window
// quadrant, if in [0,8)); remaining panels are pure copy, done cooperatively.
__global__ __launch_bounds__(256, 5)
void score_kernel(const float* __restrict__ cost, const unsigned short* __restrict__ ws,
                  float* __restrict__ out)
{
    __shared__ unsigned short Qs[32 * CC];    // [32 rows][32 ch]
    __shared__ unsigned short Ks[128 * CC];   // [128 window cols][32 ch]

    const int t    = threadIdx.x;
    const int bx   = blockIdx.x;
    const int tile = bx & 7;
    const int bh   = (bx >> 3) & 511;
    const int dir  = bx >> 12;
    const int i0   = tile * 32;
    const int wbase = dir ? i0 : (i0 - 96);   // multiple of 32
    const int wp0   = wbase >> 5;             // window panel of wave 0 (may be <0)

    // dir0 (r2l): Q from left, K from right; dir1 (l2r): Q from right, K from left
    const unsigned short* qsrc = ws + (dir ? WS_Q(1) : WS_Q(0)) + bh * WW * CC;
    const unsigned short* ksrc = ws + (dir ? WS_K(0) : WS_K(1)) + bh * WW * CC;
    const float* csrc = cost + (size_t)dir * COST1 + (size_t)bh * (WW * WW) + (size_t)i0 * WW;
    float* odst = out + O2_OFF + (size_t)dir * COST1 + (size_t)bh * (WW * WW) + (size_t)i0 * WW;

    // stage Q: rows [i0, i0+32), 2 KB
    if (t < 128) {
        ((uint4*)Qs)[t] = ((const uint4*)(qsrc + i0 * CC))[t];
    }
    // stage K: window cols [wbase, wbase+128), zero-fill OOB, 8 KB = 512 uint4
    #pragma unroll
    for (int qq = t; qq < 512; qq += 256) {
        int col = wbase + (qq >> 2);
        uint4 v = make_uint4(0u, 0u, 0u, 0u);
        if (col >= 0 && col < WW)
            v = ((const uint4*)(ksrc + col * CC))[qq & 3];
        ((uint4*)Ks)[qq] = v;
    }
    __syncthreads();   // the only barrier

    const int w = t >> 6, lane = t & 63;
    const int quad = lane >> 4, l16 = lane & 15;
    const int pw = wp0 + w;                   // absolute panel this wave's MFMA covers
    const bool wvalid = (pw >= 0 && pw < 8);

    // ---- complement-panel loads (pure copy), statically unrolled & predicated ----
    const int prow = t >> 3;                  // 0..31
    const int pc4  = 4 * (t & 7);             // 0,4,...,28
    f4v cbuf[8];
    #pragma unroll
    for (int p = 0; p < 8; ++p) {
        if (p < wp0 || p > wp0 + 3)
            cbuf[p] = __builtin_nontemporal_load((const f4v*)(csrc + prow * WW + p * 32 + pc4));
    }

    // ---- window-panel loads: lane's float4 = cost[i][jb..jb+4), matching acc layout ----
    f4v wv[2][2];
    if (wvalid) {
        #pragma unroll
        for (int nt = 0; nt < 2; ++nt)
            #pragma unroll
            for (int mt = 0; mt < 2; ++mt) {
                int i  = 16 * mt + l16;
                int jb = 32 * pw + 16 * nt + 4 * quad;
                wv[nt][mt] = __builtin_nontemporal_load((const f4v*)(csrc + i * WW + jb));
            }
    }

    // ---- fragments + swapped-operand MFMA (loads above stay in flight) ----
    bf16x8 kf[2], qf[2];
    #pragma unroll
    for (int nt = 0; nt < 2; ++nt)
        kf[nt] = *(const bf16x8*)(Ks + (32 * w + 16 * nt + l16) * CC + quad * 8);
    #pragma unroll
    for (int mt = 0; mt < 2; ++mt)
        qf[mt] = *(const bf16x8*)(Qs + (16 * mt + l16) * CC + quad * 8);

    f32x4 acc[2][2] = {};   // [nt][mt]; lane holds S[i=i0+16mt+l16][j=32pw+16nt+4quad+r]
    #pragma unroll
    for (int nt = 0; nt < 2; ++nt)
        #pragma unroll
        for (int mt = 0; mt < 2; ++mt)
            acc[nt][mt] = __builtin_amdgcn_mfma_f32_16x16x32_bf16(
                kf[nt], qf[mt], acc[nt][mt], 0, 0, 0);

    // ---- window band-add + store, all in registers ----
    if (wvalid) {
        const float inv32 = 1.0f / 32.0f;
        #pragma unroll
        for (int nt = 0; nt < 2; ++nt)
            #pragma unroll
            for (int mt = 0; mt < 2; ++mt) {
                int i  = 16 * mt + l16;
                int ia = i0 + i;
                int jb = 32 * pw + 16 * nt + 4 * quad;
                f4v v = wv[nt][mt];
                #pragma unroll
                for (int r = 0; r < 4; ++r) {
                    int j = jb + r;
                    int d = dir ? (j - ia) : (ia - j);
                    if (d >= 0 && d < CR) v[r] += acc[nt][mt][r] * inv32;
                }
                __builtin_nontemporal_store(v, (f4v*)(odst + i * WW + jb));
            }
    }

    // ---- complement-panel stores ----
    #pragma unroll
    for (int p = 0; p < 8; ++p) {
        if (p < wp0 || p > wp0 + 3)
            __builtin_nontemporal_store(cbuf[p], (f4v*)(odst + prow * WW + p * 32 + pc4));
    }
}

// ---------------- Fallback (R1 kernel) if ws too small ----------------
__global__ __launch_bounds__(256, 2)
void pab_fused(const float* __restrict__ x_left, const float* __restrict__ x_right,
               const float* __restrict__ cost,
               const float* __restrict__ q_w, const float* __restrict__ q_b,
               const float* __restrict__ q_gamma, const float* __restrict__ q_beta,
               const float* __restrict__ q_mean, const float* __restrict__ q_var,
               const float* __restrict__ k_w, const float* __restrict__ k_b,
               const float* __restrict__ k_gamma, const float* __restrict__ k_beta,
               const float* __restrict__ k_mean, const float* __restrict__ k_var,
               float* __restrict__ out)
{
    __shared__ float qwt[CC][CC];
    __shared__ float kwt[CC][CC];
    __shared__ float qbf[CC], kbf[CC], qsc[CC], ksc[CC];
    __shared__ float Qls[WW][CC];
    __shared__ float Qrs[WW][CC];

    const int t   = threadIdx.x;
    const int bid = blockIdx.x;
    const int b   = bid >> 7;
    const int h   = bid & 127;

    if (t < CC) {
        float qs = q_gamma[t] * rsqrtf(q_var[t] + EPSF);
        float ks = k_gamma[t] * rsqrtf(k_var[t] + EPSF);
        qsc[t] = qs; ksc[t] = ks;
        qbf[t] = q_b[t] * qs + q_beta[t] - q_mean[t] * qs;
        kbf[t] = k_b[t] * ks + k_beta[t] - k_mean[t] * ks;
    }
    __syncthreads();
    for (int r = t; r < CC * CC; r += 256) {
        int o = r >> 5, c = r & 31;
        qwt[c][o] = q_w[r] * qsc[o];
        kwt[c][o] = k_w[r] * ksc[o];
    }
    __syncthreads();

    float ql[CC], qr[CC], kl[CC], kr[CC];
    #pragma unroll
    for (int o = 0; o < CC; ++o) {
        float qb0 = qbf[o], kb0 = kbf[o];
        ql[o] = qb0; qr[o] = qb0; kl[o] = kb0; kr[o] = kb0;
    }
    const int xbase = (b * CC * HH + h) * WW + t;
    #pragma unroll 4
    for (int c = 0; c < CC; ++c) {
        int idx = xbase + c * (HH * WW);
        float xl = x_left[idx];
        float xr = x_right[idx];
        out[idx]          = 2.0f * xl;
        out[O1_OFF + idx] = 2.0f * xr;
        #pragma unroll
        for (int o = 0; o < CC; ++o) {
            float qw = qwt[c][o];
            float kw = kwt[c][o];
            ql[o] += xl * qw;
            kl[o] += xl * kw;
            qr[o] += xr * qw;
            kr[o] += xr * kw;
        }
    }
    #pragma unroll
    for (int o = 0; o < CC; o += 4) {
        *(float4*)&Qls[t][o] = make_float4(ql[o], ql[o+1], ql[o+2], ql[o+3]);
        *(float4*)&Qrs[t][o] = make_float4(qr[o], qr[o+1], qr[o+2], qr[o+3]);
    }
    __syncthreads();

    const int rowbase = bid * (WW * WW) + t;
    const float* __restrict__ c0 = cost + rowbase;
    const float* __restrict__ c1 = cost + COST1 + rowbase;
    float* __restrict__ o2 = out + O2_OFF + rowbase;
    float* __restrict__ o3 = out + O2_OFF + COST1 + rowbase;

    #pragma unroll 2
    for (int i = 0; i < WW; ++i) {
        float v0 = c0[i * WW];
        float v1 = c1[i * WW];
        int d = i - t;
        if (d >= 0 && d < CR) {
            float s = 0.f;
            #pragma unroll
            for (int o = 0; o < CC; o += 4) {
                float4 q = *(const float4*)&Qls[i][o];
                s += q.x * kr[o] + q.y * kr[o+1] + q.z * kr[o+2] + q.w * kr[o+3];
            }
            v0 += s * (1.0f / 32.0f);
        }
        if (d <= 0 && d > -CR) {
            float s = 0.f;
            #pragma unroll
            for (int o = 0; o < CC; o += 4) {
                float4 q = *(const float4*)&Qrs[i][o];
                s += q.x * kl[o] + q.y * kl[o+1] + q.z * kl[o+2] + q.w * kl[o+3];
            }
            v1 += s * (1.0f / 32.0f);
        }
        o2[i * WW] = v0;
        o3[i * WW] = v1;
    }
}

extern "C" void kernel_launch(void* const* d_in, const int* in_sizes, int n_in,
                              void* d_out, int out_size, void* d_ws, size_t ws_size,
                              hipStream_t stream) {
    const float* x_left  = (const float*)d_in[0];
    const float* x_right = (const float*)d_in[1];
    const float* cost    = (const float*)d_in[2];
    const float* q_w     = (const float*)d_in[3];
    const float* q_b     = (const float*)d_in[4];
    const float* q_gamma = (const float*)d_in[5];
    const float* q_beta  = (const float*)d_in[6];
    const float* q_mean  = (const float*)d_in[7];
    const float* q_var   = (const float*)d_in[8];
    const float* k_w     = (const float*)d_in[9];
    const float* k_b     = (const float*)d_in[10];
    const float* k_gamma = (const float*)d_in[11];
    const float* k_beta  = (const float*)d_in[12];
    const float* k_mean  = (const float*)d_in[13];
    const float* k_var   = (const float*)d_in[14];
    float* out = (float*)d_out;

    if (ws_size >= WS_NEEDED) {
        unsigned short* ws = (unsigned short*)d_ws;
        proj_kernel<<<dim3(1024), dim3(256), 0, stream>>>(
            x_left, x_right,
            q_w, q_b, q_gamma, q_beta, q_mean, q_var,
            k_w, k_b, k_gamma, k_beta, k_mean, k_var,
            out, ws);
        score_kernel<<<dim3(8192), dim3(256), 0, stream>>>(cost, ws, out);
    } else {
        pab_fused<<<dim3(BB * HH), dim3(256), 0, stream>>>(
            x_left, x_right, cost,
            q_w, q_b, q_gamma, q_beta, q_mean, q_var,
            k_w, k_b, k_gamma, k_beta, k_mean, k_var,
            out);
    }
}

// Round 4
// 547.273 us; speedup vs baseline: 1.0278x; 1.0278x over previous
//
#include <hip/hip_runtime.h>

#define BB 4
#define CC 32
#define HH 128
#define WW 256
#define CR 85
#define EPSF 1e-5f

// Output offsets (elements): out0 @0, out1 @4194304, out2 @8388608, out3 @41943040
#define O1_OFF 4194304
#define O2_OFF 8388608
#define COST1 33554432   // elements per direction of cost / out2-3

typedef __attribute__((ext_vector_type(8))) short bf16x8;
typedef __attribute__((ext_vector_type(4))) float f32x4;
typedef __attribute__((ext_vector_type(4))) float f4v;

// ws layout (ushort bf16): Q[side][512][256][32] then K[side][512][256][32]
// side 0 = from x_left (Q_l, K_l), side 1 = from x_right (Q_r, K_r)
#define ARR (512 * 256 * 32)
#define WS_Q(side) ((side) * ARR)
#define WS_K(side) (2 * ARR + (side) * ARR)
#define WS_NEEDED (4ull * ARR * 2ull)   // bytes

static __device__ __forceinline__ unsigned short f2bf(float f) {
    unsigned u = __float_as_uint(f);
    unsigned r = (u + 0x7FFFu + ((u >> 16) & 1u)) >> 16;   // RNE
    return (unsigned short)r;
}

// ---------------- Kernel A: projections + 2*x outputs + bf16 Q/K to ws ----------------
__global__ __launch_bounds__(256, 4)
void proj_kernel(const float* __restrict__ x_left, const float* __restrict__ x_right,
                 const float* __restrict__ q_w, const float* __restrict__ q_b,
                 const float* __restrict__ q_gamma, const float* __restrict__ q_beta,
                 const float* __restrict__ q_mean, const float* __restrict__ q_var,
                 const float* __restrict__ k_w, const float* __restrict__ k_b,
                 const float* __restrict__ k_gamma, const float* __restrict__ k_beta,
                 const float* __restrict__ k_mean, const float* __restrict__ k_var,
                 float* __restrict__ out, unsigned short* __restrict__ ws)
{
    __shared__ float wq[CC][CC];   // [c][o] BN-folded
    __shared__ float wk[CC][CC];
    __shared__ float bq[CC], bk[CC], sq[CC], sk[CC];

    const int t    = threadIdx.x;       // pixel within row
    const int side = blockIdx.x >> 9;   // 0 = left, 1 = right
    const int bh   = blockIdx.x & 511;

    if (t < CC) {
        float qs = q_gamma[t] * rsqrtf(q_var[t] + EPSF);
        float ks = k_gamma[t] * rsqrtf(k_var[t] + EPSF);
        sq[t] = qs; sk[t] = ks;
        bq[t] = q_b[t] * qs + q_beta[t] - q_mean[t] * qs;
        bk[t] = k_b[t] * ks + k_beta[t] - k_mean[t] * ks;
    }
    __syncthreads();
    for (int r = t; r < CC * CC; r += 256) {
        int o = r >> 5, c = r & 31;
        wq[c][o] = q_w[r] * sq[o];
        wk[c][o] = k_w[r] * sk[o];
    }
    __syncthreads();

    float q[CC], k[CC];
    #pragma unroll
    for (int o = 0; o < CC; ++o) { q[o] = bq[o]; k[o] = bk[o]; }

    const float* x = side ? x_right : x_left;
    const int b = bh >> 7, h = bh & 127;
    const int xbase = (b * CC * HH + h) * WW + t;
    float* outx = out + side * O1_OFF;

    #pragma unroll 4
    for (int c = 0; c < CC; ++c) {
        int idx = xbase + c * (HH * WW);
        float xv = __builtin_nontemporal_load(x + idx);
        __builtin_nontemporal_store(2.0f * xv, outx + idx);
        #pragma unroll
        for (int o = 0; o < CC; ++o) {
            q[o] += xv * wq[c][o];
            k[o] += xv * wk[c][o];
        }
    }

    // ws stores use default caching: score reads them next, keep in L2/L3
    unsigned short* qdst = ws + WS_Q(side) + (bh * WW + t) * CC;
    unsigned short* kdst = ws + WS_K(side) + (bh * WW + t) * CC;
    #pragma unroll
    for (int g = 0; g < 4; ++g) {
        uint4 vq, vk;
        vq.x = f2bf(q[8*g+0]) | ((unsigned)f2bf(q[8*g+1]) << 16);
        vq.y = f2bf(q[8*g+2]) | ((unsigned)f2bf(q[8*g+3]) << 16);
        vq.z = f2bf(q[8*g+4]) | ((unsigned)f2bf(q[8*g+5]) << 16);
        vq.w = f2bf(q[8*g+6]) | ((unsigned)f2bf(q[8*g+7]) << 16);
        vk.x = f2bf(k[8*g+0]) | ((unsigned)f2bf(k[8*g+1]) << 16);
        vk.y = f2bf(k[8*g+2]) | ((unsigned)f2bf(k[8*g+3]) << 16);
        vk.z = f2bf(k[8*g+4]) | ((unsigned)f2bf(k[8*g+5]) << 16);
        vk.w = f2bf(k[8*g+6]) | ((unsigned)f2bf(k[8*g+7]) << 16);
        ((uint4*)qdst)[g] = vq;
        ((uint4*)kdst)[g] = vk;
    }
}

// ---------------- Kernel B: MFMA scores + cost stream ----------------
// R0 skeleton (full-row 1KB/wave cost streaming + Sb exchange) with:
//  - MFMA fragments loaded DIRECTLY from global ws (per-wave contiguous,
//    lane-permuted): no Q/K LDS staging, no staging barriers. 1 barrier total.
//  - XCD-swizzled blockIdx (grid 8192, 8192%8==0 -> bijective): the 8 tiles of
//    one bh (4x-overlapping K windows) run on the same XCD -> K re-reads hit L2.
//  - cost prefetched first (nt), epilogue stores nt.
__global__ __launch_bounds__(256, 5)
void score_kernel(const float* __restrict__ cost, const unsigned short* __restrict__ ws,
                  float* __restrict__ out)
{
    __shared__ float Sb[32 * 132];   // 16.9 KB, +4 pad per row

    // XCD swizzle: hw id -> logical id; consecutive logical ids share an XCD.
    const int bx   = (blockIdx.x & 7) * 1024 + (blockIdx.x >> 3);
    const int tile = bx & 7;
    const int bh   = (bx >> 3) & 511;
    const int dir  = bx >> 12;        // 0 or 1 (bx < 8192)
    const int i0   = tile * 32;
    const int wbase = dir ? i0 : (i0 - 96);   // multiple of 32

    // dir0 (r2l): Q from left, K from right; dir1 (l2r): Q from right, K from left
    const unsigned short* qsrc = ws + (dir ? WS_Q(1) : WS_Q(0)) + bh * WW * CC;
    const unsigned short* ksrc = ws + (dir ? WS_K(0) : WS_K(1)) + bh * WW * CC;
    const float* csrc = cost + (size_t)dir * COST1 + (size_t)bh * (WW * WW);
    float* odst = out + O2_OFF + (size_t)dir * COST1 + (size_t)bh * (WW * WW);

    const int t = threadIdx.x;
    const int rowlane = t >> 6;        // 0..3
    const int c4 = 4 * (t & 63);

    // ---- cost prefetch: 8x float4/lane, nt; full-row 1KB/wave coalescing ----
    f4v vbuf[8];
    #pragma unroll
    for (int p = 0; p < 8; ++p) {
        int rl = 4 * p + rowlane;
        vbuf[p] = __builtin_nontemporal_load((const f4v*)(csrc + (i0 + rl) * WW + c4));
    }

    // ---- MFMA fragments straight from global ws ----
    const int w = t >> 6, lane = t & 63;
    const int quad = lane >> 4, l16 = lane & 15;

    bf16x8 qf[2], kf[2];
    #pragma unroll
    for (int mt = 0; mt < 2; ++mt)
        qf[mt] = *(const bf16x8*)(qsrc + (i0 + 16 * mt + l16) * CC + quad * 8);
    #pragma unroll
    for (int nt = 0; nt < 2; ++nt) {
        int col = wbase + 32 * w + 16 * nt + l16;
        bf16x8 kv = {};
        if (col >= 0 && col < WW)
            kv = *(const bf16x8*)(ksrc + col * CC + quad * 8);
        kf[nt] = kv;
    }

    f32x4 acc[2][2] = {};
    #pragma unroll
    for (int mt = 0; mt < 2; ++mt)
        #pragma unroll
        for (int nt = 0; nt < 2; ++nt)
            acc[mt][nt] = __builtin_amdgcn_mfma_f32_16x16x32_bf16(
                qf[mt], kf[nt], acc[mt][nt], 0, 0, 0);

    // ---- Sb exchange: acc fragment layout -> row-major [32][132] ----
    #pragma unroll
    for (int mt = 0; mt < 2; ++mt)
        #pragma unroll
        for (int nt = 0; nt < 2; ++nt) {
            int cl = 32 * w + 16 * nt + l16;
            #pragma unroll
            for (int r = 0; r < 4; ++r) {
                int row = 16 * mt + quad * 4 + r;
                Sb[row * 132 + cl] = acc[mt][nt][r];
            }
        }
    __syncthreads();   // the only barrier

    // ---- epilogue: band-add scores into prefetched cost, nt stores ----
    const float inv32 = 1.0f / 32.0f;
    const int lc = c4 - wbase;
    const bool inwin = (lc >= 0 && lc < 128);

    #pragma unroll
    for (int p = 0; p < 8; ++p) {
        int rl = 4 * p + rowlane;
        int i = i0 + rl;
        f4v v = vbuf[p];
        if (inwin) {
            const f4v s = *(const f4v*)(Sb + rl * 132 + lc);
            int d0 = dir ? (c4 + 0 - i) : (i - c4 - 0);
            int d1 = dir ? (c4 + 1 - i) : (i - c4 - 1);
            int d2 = dir ? (c4 + 2 - i) : (i - c4 - 2);
            int d3 = dir ? (c4 + 3 - i) : (i - c4 - 3);
            if (d0 >= 0 && d0 < CR) v[0] += s[0] * inv32;
            if (d1 >= 0 && d1 < CR) v[1] += s[1] * inv32;
            if (d2 >= 0 && d2 < CR) v[2] += s[2] * inv32;
            if (d3 >= 0 && d3 < CR) v[3] += s[3] * inv32;
        }
        __builtin_nontemporal_store(v, (f4v*)(odst + (size_t)i * WW + c4));
    }
}

// ---------------- Fallback (R1 kernel) if ws too small ----------------
__global__ __launch_bounds__(256, 2)
void pab_fused(const float* __restrict__ x_left, const float* __restrict__ x_right,
               const float* __restrict__ cost,
               const float* __restrict__ q_w, const float* __restrict__ q_b,
               const float* __restrict__ q_gamma, const float* __restrict__ q_beta,
               const float* __restrict__ q_mean, const float* __restrict__ q_var,
               const float* __restrict__ k_w, const float* __restrict__ k_b,
               const float* __restrict__ k_gamma, const float* __restrict__ k_beta,
               const float* __restrict__ k_mean, const float* __restrict__ k_var,
               float* __restrict__ out)
{
    __shared__ float qwt[CC][CC];
    __shared__ float kwt[CC][CC];
    __shared__ float qbf[CC], kbf[CC], qsc[CC], ksc[CC];
    __shared__ float Qls[WW][CC];
    __shared__ float Qrs[WW][CC];

    const int t   = threadIdx.x;
    const int bid = blockIdx.x;
    const int b   = bid >> 7;
    const int h   = bid & 127;

    if (t < CC) {
        float qs = q_gamma[t] * rsqrtf(q_var[t] + EPSF);
        float ks = k_gamma[t] * rsqrtf(k_var[t] + EPSF);
        qsc[t] = qs; ksc[t] = ks;
        qbf[t] = q_b[t] * qs + q_beta[t] - q_mean[t] * qs;
        kbf[t] = k_b[t] * ks + k_beta[t] - k_mean[t] * ks;
    }
    __syncthreads();
    for (int r = t; r < CC * CC; r += 256) {
        int o = r >> 5, c = r & 31;
        qwt[c][o] = q_w[r] * qsc[o];
        kwt[c][o] = k_w[r] * ksc[o];
    }
    __syncthreads();

    float ql[CC], qr[CC], kl[CC], kr[CC];
    #pragma unroll
    for (int o = 0; o < CC; ++o) {
        float qb0 = qbf[o], kb0 = kbf[o];
        ql[o] = qb0; qr[o] = qb0; kl[o] = kb0; kr[o] = kb0;
    }
    const int xbase = (b * CC * HH + h) * WW + t;
    #pragma unroll 4
    for (int c = 0; c < CC; ++c) {
        int idx = xbase + c * (HH * WW);
        float xl = x_left[idx];
        float xr = x_right[idx];
        out[idx]          = 2.0f * xl;
        out[O1_OFF + idx] = 2.0f * xr;
        #pragma unroll
        for (int o = 0; o < CC; ++o) {
            float qw = qwt[c][o];
            float kw = kwt[c][o];
            ql[o] += xl * qw;
            kl[o] += xl * kw;
            qr[o] += xr * qw;
            kr[o] += xr * kw;
        }
    }
    #pragma unroll
    for (int o = 0; o < CC; o += 4) {
        *(float4*)&Qls[t][o] = make_float4(ql[o], ql[o+1], ql[o+2], ql[o+3]);
        *(float4*)&Qrs[t][o] = make_float4(qr[o], qr[o+1], qr[o+2], qr[o+3]);
    }
    __syncthreads();

    const int rowbase = bid * (WW * WW) + t;
    const float* __restrict__ c0 = cost + rowbase;
    const float* __restrict__ c1 = cost + COST1 + rowbase;
    float* __restrict__ o2 = out + O2_OFF + rowbase;
    float* __restrict__ o3 = out + O2_OFF + COST1 + rowbase;

    #pragma unroll 2
    for (int i = 0; i < WW; ++i) {
        float v0 = c0[i * WW];
        float v1 = c1[i * WW];
        int d = i - t;
        if (d >= 0 && d < CR) {
            float s = 0.f;
            #pragma unroll
            for (int o = 0; o < CC; o += 4) {
                float4 q = *(const float4*)&Qls[i][o];
                s += q.x * kr[o] + q.y * kr[o+1] + q.z * kr[o+2] + q.w * kr[o+3];
            }
            v0 += s * (1.0f / 32.0f);
        }
        if (d <= 0 && d > -CR) {
            float s = 0.f;
            #pragma unroll
            for (int o = 0; o < CC; o += 4) {
                float4 q = *(const float4*)&Qrs[i][o];
                s += q.x * kl[o] + q.y * kl[o+1] + q.z * kl[o+2] + q.w * kl[o+3];
            }
            v1 += s * (1.0f / 32.0f);
        }
        o2[i * WW] = v0;
        o3[i * WW] = v1;
    }
}

extern "C" void kernel_launch(void* const* d_in, const int* in_sizes, int n_in,
                              void* d_out, int out_size, void* d_ws, size_t ws_size,
                              hipStream_t stream) {
    const float* x_left  = (const float*)d_in[0];
    const float* x_right = (const float*)d_in[1];
    const float* cost    = (const float*)d_in[2];
    const float* q_w     = (const float*)d_in[3];
    const float* q_b     = (const float*)d_in[4];
    const float* q_gamma = (const float*)d_in[5];
    const float* q_beta  = (const float*)d_in[6];
    const float* q_mean  = (const float*)d_in[7];
    const float* q_var   = (const float*)d_in[8];
    const float* k_w     = (const float*)d_in[9];
    const float* k_b     = (const float*)d_in[10];
    const float* k_gamma = (const float*)d_in[11];
    const float* k_beta  = (const float*)d_in[12];
    const float* k_mean  = (const float*)d_in[13];
    const float* k_var   = (const float*)d_in[14];
    float* out = (float*)d_out;

    if (ws_size >= WS_NEEDED) {
        unsigned short* ws = (unsigned short*)d_ws;
        proj_kernel<<<dim3(1024), dim3(256), 0, stream>>>(
            x_left, x_right,
            q_w, q_b, q_gamma, q_beta, q_mean, q_var,
            k_w, k_b, k_gamma, k_beta, k_mean, k_var,
            out, ws);
        score_kernel<<<dim3(8192), dim3(256), 0, stream>>>(cost, ws, out);
    } else {
        pab_fused<<<dim3(BB * HH), dim3(256), 0, stream>>>(
            x_left, x_right, cost,
            q_w, q_b, q_gamma, q_beta, q_mean, q_var,
            k_w, k_b, k_gamma, k_beta, k_mean, k_var,
            out);
    }
}

// Round 5
// 531.373 us; speedup vs baseline: 1.0585x; 1.0299x over previous
//
#include <hip/hip_runtime.h>

#define BB 4
#define CC 32
#define HH 128
#define WW 256
#define CR 85
#define EPSF 1e-5f

// Output offsets (elements): out0 @0, out1 @4194304, out2 @8388608, out3 @41943040
#define O1_OFF 4194304
#define O2_OFF 8388608
#define COST1 33554432   // elements per direction of cost / out2-3

typedef __attribute__((ext_vector_type(8))) short bf16x8;
typedef __attribute__((ext_vector_type(4))) float f32x4;
typedef __attribute__((ext_vector_type(4))) float f4v;

static __device__ __forceinline__ unsigned short f2bf(float f) {
    unsigned u = __float_as_uint(f);
    unsigned r = (u + 0x7FFFu + ((u >> 16) & 1u)) >> 16;   // RNE
    return (unsigned short)r;
}

// ---------------- Fused kernel: projection + 2*x outputs + MFMA scores + cost stream ----
// block = (dir, bh). No workspace round-trip: Q/K for the whole 256-px row are
// projected into LDS once, then the 8 row-tiles stream cost->out with the proven
// R0 score body (prefetch-nt -> MFMA -> Sb exchange -> band-add -> nt store).
// LDS: Qs 16K + Ks 16K + smem 16.9K (Sb overlaid on BN-folded weights, which are
// dead after the projection phase) = 48.5 KB -> 3 blocks/CU.
__global__ __launch_bounds__(256, 3)
void pab_fused_one(const float* __restrict__ x_left, const float* __restrict__ x_right,
                   const float* __restrict__ cost,
                   const float* __restrict__ q_w, const float* __restrict__ q_b,
                   const float* __restrict__ q_gamma, const float* __restrict__ q_beta,
                   const float* __restrict__ q_mean, const float* __restrict__ q_var,
                   const float* __restrict__ k_w, const float* __restrict__ k_b,
                   const float* __restrict__ k_gamma, const float* __restrict__ k_beta,
                   const float* __restrict__ k_mean, const float* __restrict__ k_var,
                   float* __restrict__ out)
{
    __shared__ unsigned short Qs[WW * CC];   // [px][ch] bf16, 16 KB
    __shared__ unsigned short Ks[WW * CC];   // [px][ch] bf16, 16 KB
    __shared__ char smem[32 * 132 * 4];      // 16.9 KB: weights (phase 1) / Sb (phase 2)
    float* Sb = (float*)smem;                          // [32][132] fp32
    float (*wqs)[CC] = (float(*)[CC])smem;             // [c][o], 4 KB
    float (*wks)[CC] = (float(*)[CC])(smem + 4096);    // 4 KB
    float* bqs = (float*)(smem + 8192);                // 128 B
    float* bks = (float*)(smem + 8320);
    float* sqs = (float*)(smem + 8448);
    float* sks = (float*)(smem + 8576);

    const int t   = threadIdx.x;      // px within row
    const int dir = blockIdx.x >> 9;  // 0 = r2l, 1 = l2r
    const int bh  = blockIdx.x & 511;
    const int b = bh >> 7, h = bh & 127;

    // ---- phase 1a: BN fold ----
    if (t < CC) {
        float qs_ = q_gamma[t] * rsqrtf(q_var[t] + EPSF);
        float ks_ = k_gamma[t] * rsqrtf(k_var[t] + EPSF);
        sqs[t] = qs_; sks[t] = ks_;
        bqs[t] = q_b[t] * qs_ + q_beta[t] - q_mean[t] * qs_;
        bks[t] = k_b[t] * ks_ + k_beta[t] - k_mean[t] * ks_;
    }
    __syncthreads();
    for (int r = t; r < CC * CC; r += 256) {
        int o = r >> 5, c = r & 31;
        wqs[c][o] = q_w[r] * sqs[o];
        wks[c][o] = k_w[r] * sks[o];
    }
    __syncthreads();

    // ---- phase 1b: project Q (dir's Q side) and K (other side) for the full row ----
    // dir0 (r2l): Q from left, K from right; dir1 (l2r): Q from right, K from left
    const float* xq = dir ? x_right : x_left;
    const float* xk = dir ? x_left  : x_right;
    float* outq = out + (dir ? O1_OFF : 0);     // this dir owns its Q side's 2*x copy
    const int xbase = (b * CC * HH + h) * WW + t;

    {
        float q[CC];
        #pragma unroll
        for (int o = 0; o < CC; ++o) q[o] = bqs[o];
        #pragma unroll 4
        for (int c = 0; c < CC; ++c) {
            int idx = xbase + c * (HH * WW);
            float xv = xq[idx];                               // read 2x total: keep cached
            __builtin_nontemporal_store(2.0f * xv, outq + idx);
            #pragma unroll
            for (int o = 0; o < CC; ++o) q[o] += xv * wqs[c][o];
        }
        unsigned short* qdst = Qs + t * CC;
        #pragma unroll
        for (int g = 0; g < 4; ++g) {
            uint4 v;
            v.x = f2bf(q[8*g+0]) | ((unsigned)f2bf(q[8*g+1]) << 16);
            v.y = f2bf(q[8*g+2]) | ((unsigned)f2bf(q[8*g+3]) << 16);
            v.z = f2bf(q[8*g+4]) | ((unsigned)f2bf(q[8*g+5]) << 16);
            v.w = f2bf(q[8*g+6]) | ((unsigned)f2bf(q[8*g+7]) << 16);
            ((uint4*)qdst)[g] = v;
        }
    }
    {
        float k[CC];
        #pragma unroll
        for (int o = 0; o < CC; ++o) k[o] = bks[o];
        #pragma unroll 4
        for (int c = 0; c < CC; ++c) {
            float xv = xk[xbase + c * (HH * WW)];
            #pragma unroll
            for (int o = 0; o < CC; ++o) k[o] += xv * wks[c][o];
        }
        unsigned short* kdst = Ks + t * CC;
        #pragma unroll
        for (int g = 0; g < 4; ++g) {
            uint4 v;
            v.x = f2bf(k[8*g+0]) | ((unsigned)f2bf(k[8*g+1]) << 16);
            v.y = f2bf(k[8*g+2]) | ((unsigned)f2bf(k[8*g+3]) << 16);
            v.z = f2bf(k[8*g+4]) | ((unsigned)f2bf(k[8*g+5]) << 16);
            v.w = f2bf(k[8*g+6]) | ((unsigned)f2bf(k[8*g+7]) << 16);
            ((uint4*)kdst)[g] = v;
        }
    }
    __syncthreads();   // Qs/Ks ready; weights now dead (Sb may overwrite after next barrier)

    // ---- phase 2: 8 row-tiles of MFMA + cost stream ----
    const float* csrc = cost + (size_t)dir * COST1 + (size_t)bh * (WW * WW);
    float* odst = out + O2_OFF + (size_t)dir * COST1 + (size_t)bh * (WW * WW);
    const int rowlane = t >> 6;        // 0..3
    const int c4 = 4 * (t & 63);
    const int w = t >> 6, lane = t & 63;
    const int quad = lane >> 4, l16 = lane & 15;
    const float inv32 = 1.0f / 32.0f;

    for (int tile = 0; tile < 8; ++tile) {
        const int i0 = tile * 32;
        const int wbase = dir ? i0 : (i0 - 96);   // window cols [wbase, wbase+128)

        // cost prefetch: 8x float4/lane, nt; full-row 1KB/wave coalescing
        f4v vbuf[8];
        #pragma unroll
        for (int p = 0; p < 8; ++p) {
            int rl = 4 * p + rowlane;
            vbuf[p] = __builtin_nontemporal_load((const f4v*)(csrc + (i0 + rl) * WW + c4));
        }

        // fragments from LDS-resident row Q/K; OOB window cols -> zero frag
        bf16x8 qf[2], kf[2];
        #pragma unroll
        for (int mt = 0; mt < 2; ++mt)
            qf[mt] = *(const bf16x8*)(Qs + (i0 + 16 * mt + l16) * CC + quad * 8);
        #pragma unroll
        for (int nt = 0; nt < 2; ++nt) {
            int col = wbase + 32 * w + 16 * nt + l16;
            bf16x8 kv = {};
            if (col >= 0 && col < WW)
                kv = *(const bf16x8*)(Ks + col * CC + quad * 8);
            kf[nt] = kv;
        }

        f32x4 acc[2][2] = {};
        #pragma unroll
        for (int mt = 0; mt < 2; ++mt)
            #pragma unroll
            for (int nt = 0; nt < 2; ++nt)
                acc[mt][nt] = __builtin_amdgcn_mfma_f32_16x16x32_bf16(
                    qf[mt], kf[nt], acc[mt][nt], 0, 0, 0);

        __syncthreads();   // previous tile's Sb reads (and phase-1 weight reads) complete

        // Sb exchange: acc fragment layout -> row-major [32][132]
        #pragma unroll
        for (int mt = 0; mt < 2; ++mt)
            #pragma unroll
            for (int nt = 0; nt < 2; ++nt) {
                int cl = 32 * w + 16 * nt + l16;
                #pragma unroll
                for (int r = 0; r < 4; ++r) {
                    int row = 16 * mt + quad * 4 + r;
                    Sb[row * 132 + cl] = acc[mt][nt][r];
                }
            }
        __syncthreads();

        // epilogue: band-add scores into prefetched cost, nt stores
        const int lc = c4 - wbase;
        const bool inwin = (lc >= 0 && lc < 128);
        #pragma unroll
        for (int p = 0; p < 8; ++p) {
            int rl = 4 * p + rowlane;
            int i = i0 + rl;
            f4v v = vbuf[p];
            if (inwin) {
                const f4v s = *(const f4v*)(Sb + rl * 132 + lc);
                int d0 = dir ? (c4 + 0 - i) : (i - c4 - 0);
                int d1 = dir ? (c4 + 1 - i) : (i - c4 - 1);
                int d2 = dir ? (c4 + 2 - i) : (i - c4 - 2);
                int d3 = dir ? (c4 + 3 - i) : (i - c4 - 3);
                if (d0 >= 0 && d0 < CR) v[0] += s[0] * inv32;
                if (d1 >= 0 && d1 < CR) v[1] += s[1] * inv32;
                if (d2 >= 0 && d2 < CR) v[2] += s[2] * inv32;
                if (d3 >= 0 && d3 < CR) v[3] += s[3] * inv32;
            }
            __builtin_nontemporal_store(v, (f4v*)(odst + (size_t)i * WW + c4));
        }
    }
}

extern "C" void kernel_launch(void* const* d_in, const int* in_sizes, int n_in,
                              void* d_out, int out_size, void* d_ws, size_t ws_size,
                              hipStream_t stream) {
    const float* x_left  = (const float*)d_in[0];
    const float* x_right = (const float*)d_in[1];
    const float* cost    = (const float*)d_in[2];
    const float* q_w     = (const float*)d_in[3];
    const float* q_b     = (const float*)d_in[4];
    const float* q_gamma = (const float*)d_in[5];
    const float* q_beta  = (const float*)d_in[6];
    const float* q_mean  = (const float*)d_in[7];
    const float* q_var   = (const float*)d_in[8];
    const float* k_w     = (const float*)d_in[9];
    const float* k_b     = (const float*)d_in[10];
    const float* k_gamma = (const float*)d_in[11];
    const float* k_beta  = (const float*)d_in[12];
    const float* k_mean  = (const float*)d_in[13];
    const float* k_var   = (const float*)d_in[14];
    float* out = (float*)d_out;

    pab_fused_one<<<dim3(1024), dim3(256), 0, stream>>>(
        x_left, x_right, cost,
        q_w, q_b, q_gamma, q_beta, q_mean, q_var,
        k_w, k_b, k_gamma, k_beta, k_mean, k_var,
        out);
}